// Round 9
// baseline (254.469 us; speedup 1.0000x reference)
//
#include <hip/hip_runtime.h>

#define NB   2048
#define SEQ  200
#define DIM  64
#define NH1  64
#define NH2  16
#define EPSF 1e-9f
#define LOG2E 1.442695040888963f

typedef float    fvec4 __attribute__((ext_vector_type(4)));
typedef short    svec8 __attribute__((ext_vector_type(8)));   // 8 bf16 = 4 VGPRs
typedef unsigned uvec4 __attribute__((ext_vector_type(4)));

// LDS layout (bytes). h1f = 4 waves x {tileA, tileB} x 2 KB; the setup-only
// Wc frag region (8 KB) aliases h1f[0:8K] (fenced by the second barrier).
#define H1F_OFF   0        // 16384 B
#define WCB_OFF   0        // setup alias
#define QPART_OFF 16384    // 1024 B : qterm partials (setup) / outp (epilogue)
#define QALL_OFF  17408    // 256 B  : qterm[64]
#define SMEM_BYTES 17664

__device__ __forceinline__ short f2bf(float f) {
    unsigned u = __float_as_uint(f);
    u += 0x7fffu + ((u >> 16) & 1u);      // round-to-nearest-even
    return (short)(u >> 16);
}

// packed f32x2 -> bf16x2 (RNE), 1 instruction
__device__ __forceinline__ unsigned pkbf(float lo, float hi) {
    unsigned r;
    asm("v_cvt_pk_bf16_f32 %0, %1, %2" : "=v"(r) : "v"(lo), "v"(hi));
    return r;
}
// raw v_exp_f32: D = 2^S0
__device__ __forceinline__ float exp2fast(float x) {
    float r;
    asm("v_exp_f32 %0, %1" : "=v"(r) : "v"(x));
    return r;
}

__global__ __launch_bounds__(256, 3)
void din_attn_kernel(const float* __restrict__ q,        // [B,64]
                     const float* __restrict__ key,      // [B,200,64]
                     const int*   __restrict__ seqlen,   // [B,1]
                     const float* __restrict__ W1,       // [256,64]
                     const float* __restrict__ alpha1v,
                     const float* __restrict__ mean1v,
                     const float* __restrict__ var1v,
                     const float* __restrict__ W2,       // [64,16]
                     const float* __restrict__ alpha2v,
                     const float* __restrict__ mean2v,
                     const float* __restrict__ var2v,
                     const float* __restrict__ W3,       // [16]
                     float* __restrict__ out)            // [B,64]
{
    __shared__ __align__(16) char smem[SMEM_BYTES];
    char*  wcb   = smem + WCB_OFF;                 // setup Wc frags
    char*  h1f   = smem + H1F_OFF;                 // main-loop (aliases wcb)
    float* qpart = (float*)(smem + QPART_OFF);
    float* qall  = (float*)(smem + QALL_OFF);
    float* outp  = (float*)(smem + QPART_OFF);     // epilogue alias

    const int b    = blockIdx.x;
    const int t    = threadIdx.x;
    const int lane = t & 63;
    const int wave = __builtin_amdgcn_readfirstlane(t >> 6);
    const int qd4  = lane >> 4;     // quad 0..3
    const int m    = lane & 15;

    const float* qrow = q + (size_t)b * DIM;
    const float* kb   = key + (size_t)b * (SEQ * DIM);
    int nseq = seqlen[b];
    nseq = nseq < SEQ ? nseq : SEQ;

    // ---- first iteration's two k-tiles issued BEFORE setup: latency hides
    //      under the W1 loads + both barriers.  Clamped rows -> always safe.
    int rb = wave * 32;                       // this wave's rows, stride 128
    int rmA = rb + m;       rmA = rmA < SEQ ? rmA : SEQ - 1;
    int rmB = rb + 16 + m;  rmB = rmB < SEQ ? rmB : SEQ - 1;
    const float* arp = kb + rmA * DIM + (qd4 << 3);
    const float* brp = kb + rmB * DIM + (qd4 << 3);
    fvec4 fA0 = *(const fvec4*)(arp);
    fvec4 fA1 = *(const fvec4*)(arp + 4);
    fvec4 fA2 = *(const fvec4*)(arp + 32);
    fvec4 fA3 = *(const fvec4*)(arp + 36);
    fvec4 fB0 = *(const fvec4*)(brp);
    fvec4 fB1 = *(const fvec4*)(brp + 4);
    fvec4 fB2 = *(const fvec4*)(brp + 32);
    fvec4 fB3 = *(const fvec4*)(brp + 36);

    // ---- setup 1: Wc = (W1b - W1c) + q[d]*W1d written as bf16 in frag
    //      layout; qterm partials.  Element (d,h) -> frag=(h>>4)*2+(d>>5),
    //      slot=((d>>3)&3)*16+(h&15), byte j=(d&7)*2.
    {
        const int h  = lane;
        const int c  = h >> 4;
        const int mm = h & 15;
        float qt = 0.f;
        #pragma unroll
        for (int i = 0; i < 16; ++i) {
            const int d = wave * 16 + i;
            const float qdv  = qrow[d];
            const float w1a  = W1[(d)       * NH1 + h];
            const float w1b  = W1[(64 + d)  * NH1 + h];
            const float w1c  = W1[(128 + d) * NH1 + h];
            const float w1dd = W1[(192 + d) * NH1 + h];
            const float wc   = (w1b - w1c) + qdv * w1dd;
            qt = fmaf(qdv, w1a + w1c, qt);
            const int frag = (c << 1) | (d >> 5);
            const int ln   = (((d >> 3) & 3) << 4) | mm;
            *(short*)(wcb + (frag << 10) + (ln << 4) + ((d & 7) << 1)) = f2bf(wc);
        }
        qpart[wave * 64 + h] = qt;
    }
    __syncthreads();

    // ---- setup 2: qterm reduce; frags to registers; params
    if (t < 64)
        qall[t] = (qpart[t] + qpart[64 + t]) + (qpart[128 + t] + qpart[192 + t]);

    svec8 wcf[4][2];   // Wc B-frags (phase-1 B operand)
    #pragma unroll
    for (int c = 0; c < 4; ++c)
        #pragma unroll
        for (int kk = 0; kk < 2; ++kk)
            wcf[c][kk] = *(const svec8*)(wcb + (((c << 1) | kk) << 10) + (lane << 4));

    // W2 frags, consumed as the *A* operand of the transposed phase-2:
    // A[row=j=m][k=h=kk*32+qd4*8+jj] = W2[h][j].
    svec8 w2f[2];
    #pragma unroll
    for (int kk = 0; kk < 2; ++kk) {
        svec8 f;
        #pragma unroll
        for (int j = 0; j < 8; ++j) {
            const int h = kk * 32 + qd4 * 8 + j;
            f[j] = f2bf(W2[h * NH2 + m]);
        }
        w2f[kk] = f;
    }

    // dice1 params for h = c*16 + m; r1p pre-scaled by log2(e) (raw v_exp)
    float a1p[4], m1p[4], r1p[4];
    #pragma unroll
    for (int c = 0; c < 4; ++c) {
        a1p[c] = alpha1v[c * 16 + m];
        m1p[c] = mean1v[c * 16 + m];
        r1p[c] = rsqrtf(var1v[c * 16 + m] + EPSF) * LOG2E;
    }
    // dice2 params for j = qd4*4 + reg (transposed phase-2 output rows)
    float a2p[4], m2p[4], r2p[4], w3p[4];
    #pragma unroll
    for (int reg = 0; reg < 4; ++reg) {
        const int j = qd4 * 4 + reg;
        a2p[reg] = alpha2v[j];
        m2p[reg] = mean2v[j];
        r2p[reg] = rsqrtf(var2v[j] + EPSF) * LOG2E;
        w3p[reg] = W3[j];
    }

    __syncthreads();   // wcb reads done -> h1f alias safe; qall ready

    float qtermv[4];
    #pragma unroll
    for (int c = 0; c < 4; ++c) qtermv[c] = qall[c * 16 + m];

    char* myh1a = h1f + (wave << 12);          // 2 KB tile-A transpose buffer
    char* myh1b = myh1a + 2048;                // 2 KB tile-B transpose buffer

    fvec4 oa0 = (fvec4){0.f,0.f,0.f,0.f};   // out cols qd4*8+0..3
    fvec4 oa1 = (fvec4){0.f,0.f,0.f,0.f};   // out cols qd4*8+4..7
    fvec4 oa2 = (fvec4){0.f,0.f,0.f,0.f};   // out cols 32+qd4*8+0..3
    fvec4 oa3 = (fvec4){0.f,0.f,0.f,0.f};   // out cols 32+qd4*8+4..7

    // ---- barrier-free dual-tile main loop: wave owns rows [rb, rb+32),
    //      rb += 128.  Tiles A and B are independent chains -> in-wave ILP.
    if (rb < nseq) {
        for (;;) {
            // A-frags via packed bf16 converts (both tiles)
            uvec4 uA0, uA1, uB0, uB1;
            uA0[0] = pkbf(fA0[0], fA0[1]);  uA0[1] = pkbf(fA0[2], fA0[3]);
            uA0[2] = pkbf(fA1[0], fA1[1]);  uA0[3] = pkbf(fA1[2], fA1[3]);
            uA1[0] = pkbf(fA2[0], fA2[1]);  uA1[1] = pkbf(fA2[2], fA2[3]);
            uA1[2] = pkbf(fA3[0], fA3[1]);  uA1[3] = pkbf(fA3[2], fA3[3]);
            uB0[0] = pkbf(fB0[0], fB0[1]);  uB0[1] = pkbf(fB0[2], fB0[3]);
            uB0[2] = pkbf(fB1[0], fB1[1]);  uB0[3] = pkbf(fB1[2], fB1[3]);
            uB1[0] = pkbf(fB2[0], fB2[1]);  uB1[1] = pkbf(fB2[2], fB2[3]);
            uB1[2] = pkbf(fB3[0], fB3[1]);  uB1[3] = pkbf(fB3[2], fB3[3]);
            const svec8 aA0 = __builtin_bit_cast(svec8, uA0);
            const svec8 aA1 = __builtin_bit_cast(svec8, uA1);
            const svec8 aB0 = __builtin_bit_cast(svec8, uB0);
            const svec8 aB1 = __builtin_bit_cast(svec8, uB1);

            // ---- phase 1 (both tiles): x = k @ Wc + qterm
            fvec4 accA[4], accB[4];
            #pragma unroll
            for (int c = 0; c < 4; ++c) {
                fvec4 aa = (fvec4){qtermv[c], qtermv[c], qtermv[c], qtermv[c]};
                fvec4 ab = aa;
                aa = __builtin_amdgcn_mfma_f32_16x16x32_bf16(aA0, wcf[c][0], aa, 0, 0, 0);
                ab = __builtin_amdgcn_mfma_f32_16x16x32_bf16(aB0, wcf[c][0], ab, 0, 0, 0);
                aa = __builtin_amdgcn_mfma_f32_16x16x32_bf16(aA1, wcf[c][1], aa, 0, 0, 0);
                ab = __builtin_amdgcn_mfma_f32_16x16x32_bf16(aB1, wcf[c][1], ab, 0, 0, 0);
                accA[c] = aa;  accB[c] = ab;
            }

            // ---- dice1 (both tiles); h1 -> per-tile LDS buffers,
            //      XOR-swizzled slots
            #pragma unroll
            for (int c = 0; c < 4; ++c) {
                const int kk2 = c >> 1;
                const int qhi = (c & 1) * 2 + (m >> 3);
                #pragma unroll
                for (int reg = 0; reg < 4; ++reg) {
                    const int l2  = (qhi << 4) | ((qd4 << 2) | reg);
                    const int l2s = l2 ^ ((l2 >> 3) & 7);
                    const int off = (kk2 << 10) + (l2s << 4) + ((m & 7) << 1);
                    {
                        const float x  = accA[c][reg];
                        const float tn = (x - m1p[c]) * r1p[c];
                        const float p  = __builtin_amdgcn_rcpf(1.f + exp2fast(-tn));
                        const float h1 = x * fmaf(p, 1.f - a1p[c], a1p[c]);
                        *(short*)(myh1a + off) = f2bf(h1);
                    }
                    {
                        const float x  = accB[c][reg];
                        const float tn = (x - m1p[c]) * r1p[c];
                        const float p  = __builtin_amdgcn_rcpf(1.f + exp2fast(-tn));
                        const float h1 = x * fmaf(p, 1.f - a1p[c], a1p[c]);
                        *(short*)(myh1b + off) = f2bf(h1);
                    }
                }
            }
            // same-wave write->read; compiler inserts lgkmcnt, no barrier

            // ---- phase 2 (operand-swapped, both tiles): h2^T = W2^T @ h1^T
            const int slot = lane ^ ((lane >> 3) & 7);
            const svec8 bA0 = *(const svec8*)(myh1a + (slot << 4));
            const svec8 bA1 = *(const svec8*)(myh1a + 1024 + (slot << 4));
            const svec8 bB0 = *(const svec8*)(myh1b + (slot << 4));
            const svec8 bB1 = *(const svec8*)(myh1b + 1024 + (slot << 4));
            fvec4 c2A = (fvec4){0.f, 0.f, 0.f, 0.f};
            fvec4 c2B = (fvec4){0.f, 0.f, 0.f, 0.f};
            c2A = __builtin_amdgcn_mfma_f32_16x16x32_bf16(w2f[0], bA0, c2A, 0, 0, 0);
            c2B = __builtin_amdgcn_mfma_f32_16x16x32_bf16(w2f[0], bB0, c2B, 0, 0, 0);
            c2A = __builtin_amdgcn_mfma_f32_16x16x32_bf16(w2f[1], bA1, c2A, 0, 0, 0);
            c2B = __builtin_amdgcn_mfma_f32_16x16x32_bf16(w2f[1], bB1, c2B, 0, 0, 0);

            // ---- dice2 + W3 (both tiles); 2 shfl_xor each
            float sA = 0.f, sB = 0.f;
            #pragma unroll
            for (int reg = 0; reg < 4; ++reg) {
                {
                    const float x  = c2A[reg];
                    const float tn = (x - m2p[reg]) * r2p[reg];
                    const float p  = __builtin_amdgcn_rcpf(1.f + exp2fast(-tn));
                    sA = fmaf(x * fmaf(p, 1.f - a2p[reg], a2p[reg]), w3p[reg], sA);
                }
                {
                    const float x  = c2B[reg];
                    const float tn = (x - m2p[reg]) * r2p[reg];
                    const float p  = __builtin_amdgcn_rcpf(1.f + exp2fast(-tn));
                    sB = fmaf(x * fmaf(p, 1.f - a2p[reg], a2p[reg]), w3p[reg], sB);
                }
            }
            sA += __shfl_xor(sA, 16);
            sB += __shfl_xor(sB, 16);
            sA += __shfl_xor(sA, 32);
            sB += __shfl_xor(sB, 32);
            const float wA = (rb + m < nseq)
                ? __builtin_amdgcn_rcpf(1.f + exp2fast(-sA * LOG2E)) : 0.f;
            const float wB = (rb + 16 + m < nseq)
                ? __builtin_amdgcn_rcpf(1.f + exp2fast(-sB * LOG2E)) : 0.f;

            // ---- phase 3: accumulate both tiles from registers we hold
            #pragma unroll
            for (int jj = 0; jj < 4; ++jj) {
                oa0[jj] = fmaf(wA, fA0[jj], fmaf(wB, fB0[jj], oa0[jj]));
                oa1[jj] = fmaf(wA, fA1[jj], fmaf(wB, fB1[jj], oa1[jj]));
                oa2[jj] = fmaf(wA, fA2[jj], fmaf(wB, fB2[jj], oa2[jj]));
                oa3[jj] = fmaf(wA, fA3[jj], fmaf(wB, fB3[jj], oa3[jj]));
            }

            const int rbn = rb + 128;
            if (rbn >= nseq) break;                    // wave-uniform
            rb = rbn;
            rmA = rb + m;       rmA = rmA < SEQ ? rmA : SEQ - 1;
            rmB = rb + 16 + m;  rmB = rmB < SEQ ? rmB : SEQ - 1;
            const float* ar2 = kb + rmA * DIM + (qd4 << 3);
            const float* br2 = kb + rmB * DIM + (qd4 << 3);
            fA0 = *(const fvec4*)(ar2);
            fA1 = *(const fvec4*)(ar2 + 4);
            fA2 = *(const fvec4*)(ar2 + 32);
            fA3 = *(const fvec4*)(ar2 + 36);
            fB0 = *(const fvec4*)(br2);
            fB1 = *(const fvec4*)(br2 + 4);
            fB2 = *(const fvec4*)(br2 + 32);
            fB3 = *(const fvec4*)(br2 + 36);
        }
    }

    // ---- once-per-kernel reduce over the 16 m-lanes of each q-group
    #pragma unroll
    for (int step = 1; step < 16; step <<= 1) {
        #pragma unroll
        for (int jj = 0; jj < 4; ++jj) {
            oa0[jj] += __shfl_xor(oa0[jj], step);
            oa1[jj] += __shfl_xor(oa1[jj], step);
            oa2[jj] += __shfl_xor(oa2[jj], step);
            oa3[jj] += __shfl_xor(oa3[jj], step);
        }
    }
    if (m == 0) {
        float* op = outp + wave * 64 + (qd4 << 3);
        *(fvec4*)(op)          = oa0;
        *(fvec4*)(op + 4)      = oa1;
        *(fvec4*)(op + 32)     = oa2;
        *(fvec4*)(op + 36)     = oa3;
    }
    __syncthreads();
    if (t < 64) {
        out[(size_t)b * DIM + t] = (outp[t] + outp[64 + t]) +
                                   (outp[128 + t] + outp[192 + t]);
    }
}

extern "C" void kernel_launch(void* const* d_in, const int* in_sizes, int n_in,
                              void* d_out, int out_size, void* d_ws, size_t ws_size,
                              hipStream_t stream) {
    const float* q      = (const float*)d_in[0];
    const float* key    = (const float*)d_in[1];
    const int*   seqlen = (const int*)d_in[2];
    const float* W1     = (const float*)d_in[3];
    const float* alpha1 = (const float*)d_in[4];
    const float* mean1  = (const float*)d_in[5];
    const float* var1   = (const float*)d_in[6];
    const float* W2     = (const float*)d_in[7];
    const float* alpha2 = (const float*)d_in[8];
    const float* mean2  = (const float*)d_in[9];
    const float* var2   = (const float*)d_in[10];
    const float* W3     = (const float*)d_in[11];
    float* out          = (float*)d_out;

    din_attn_kernel<<<NB, 256, 0, stream>>>(q, key, seqlen, W1,
                                            alpha1, mean1, var1,
                                            W2, alpha2, mean2, var2,
                                            W3, out);
}